// Round 12
// baseline (405.465 us; speedup 1.0000x reference)
//
#include <hip/hip_runtime.h>
#include <hip/hip_fp16.h>

// ---------------------------------------------------------------------------
// Problem constants (from reference)
// ---------------------------------------------------------------------------
#define B_GRAPHS 64
#define LMAX 1024
#define NP_TOT 49152      // sum(LENS)
#define NC_TOT 2560       // 64*40
#define EP_TOT 393216     // 8 * NP
#define EC_TOT 10240      // 4 * NC

#define SCAN_N   (NP_TOT + NC_TOT)   // 51712
#define SCAN_BLK 512
#define SCAN_NB  (SCAN_N / SCAN_BLK) // 101 (exact)

typedef _Float16 f16x8 __attribute__((ext_vector_type(8)));
typedef _Float16 f16x4 __attribute__((ext_vector_type(4)));
typedef _Float16 f16x2 __attribute__((ext_vector_type(2)));
typedef float    f32x4 __attribute__((ext_vector_type(4)));

__device__ __forceinline__ float lrelu(float x) { return x > 0.f ? x : 0.01f * x; }

// ---------------------------------------------------------------------------
// CSR build (fused, both graphs)
// ---------------------------------------------------------------------------
__global__ void zero_int_kernel(int* p, int n) {
    int i = blockIdx.x * blockDim.x + threadIdx.x;
    if (i < n) p[i] = 0;
}

__global__ void hist2_kernel(const int* __restrict__ ptgt, int* __restrict__ pdeg,
                             const int* __restrict__ ctgt, int* __restrict__ cdeg) {
    int e = blockIdx.x * blockDim.x + threadIdx.x;
    if (e < EP_TOT) atomicAdd(&pdeg[ptgt[e]], 1);
    else if (e < EP_TOT + EC_TOT) atomicAdd(&cdeg[ctgt[e - EP_TOT]], 1);
}

// ---- parallel exclusive scan over the concatenated degree array ----
__global__ __launch_bounds__(256) void scan_bsum_kernel(
    const int* __restrict__ deg, int* __restrict__ bsums)
{
    __shared__ int red[256];
    int b = blockIdx.x, t = threadIdx.x;
    int2 e = *(const int2*)(deg + b * SCAN_BLK + t * 2);
    red[t] = e.x + e.y;
    __syncthreads();
    for (int s = 128; s > 0; s >>= 1) {
        if (t < s) red[t] += red[t + s];
        __syncthreads();
    }
    if (t == 0) bsums[b] = red[0];
}

__global__ __launch_bounds__(128) void scan_sums_kernel(int* __restrict__ bsums)
{
    __shared__ int v[SCAN_NB];
    int t = threadIdx.x;
    if (t < SCAN_NB) v[t] = bsums[t];
    __syncthreads();
    if (t == 0) {
        int run = 0;
        for (int i = 0; i < SCAN_NB; ++i) { int x = v[i]; v[i] = run; run += x; }
    }
    __syncthreads();
    if (t < SCAN_NB) bsums[t] = v[t];
}

__global__ __launch_bounds__(256) void scan_final_kernel(
    const int* __restrict__ deg, const int* __restrict__ bsums,
    int* __restrict__ p_rowptr, int* __restrict__ c_rowptr)
{
    __shared__ int wsum[4];
    int b = blockIdx.x, t = threadIdx.x;
    int i = b * SCAN_BLK + t * 2;
    int2 e = *(const int2*)(deg + i);
    int ts = e.x + e.y;
    int lane = t & 63, wv = t >> 6;
    int x = ts;
    #pragma unroll
    for (int o = 1; o < 64; o <<= 1) {
        int y = __shfl_up(x, o);
        if (lane >= o) x += y;
    }
    if (lane == 63) wsum[wv] = x;
    __syncthreads();
    int base = bsums[b];
    for (int w = 0; w < wv; ++w) base += wsum[w];
    int excl = base + x - ts;
    int v0 = excl, v1 = excl + e.x;
    if (i < NP_TOT) p_rowptr[i] = v0; else c_rowptr[i - NP_TOT] = v0 - EP_TOT;
    if (i + 1 < NP_TOT) p_rowptr[i + 1] = v1; else c_rowptr[i + 1 - NP_TOT] = v1 - EP_TOT;
    if (b == 0 && t == 0) { p_rowptr[NP_TOT] = EP_TOT; c_rowptr[NC_TOT] = EC_TOT; }
}

__global__ void scatter2_kernel(const int* __restrict__ ps, const int* __restrict__ pt,
                                const int* __restrict__ prow, int* __restrict__ pcur,
                                int* __restrict__ pcsr,
                                const int* __restrict__ cs, const int* __restrict__ ct,
                                const int* __restrict__ crow, int* __restrict__ ccur,
                                int* __restrict__ ccsr) {
    int e = blockIdx.x * blockDim.x + threadIdx.x;
    if (e < EP_TOT) {
        int t = pt[e];
        int pos = atomicAdd(&pcur[t], 1);
        pcsr[prow[t] + pos] = ps[e];
    } else if (e < EP_TOT + EC_TOT) {
        int e2 = e - EP_TOT;
        int t = ct[e2];
        int pos = atomicAdd(&ccur[t], 1);
        ccsr[crow[t] + pos] = cs[e2];
    }
}

// ---------------------------------------------------------------------------
// fused weight prep: 13 jobs in one launch (blockIdx.z selects)
// ---------------------------------------------------------------------------
struct WJob { const float* in; _Float16* out; int K, D, Kp, mode; };
struct WJobs { WJob j[13]; };

__global__ __launch_bounds__(256) void wprep_all_kernel(WJobs jobs) {
    WJob jb = jobs.j[blockIdx.z];
    int idx = blockIdx.x * 256 + threadIdx.x;
    int total = jb.D * jb.Kp;
    if (idx >= total) return;
    float v;
    if (jb.mode == 0) {
        int d = idx / jb.Kp, k = idx - d * jb.Kp;
        v = (k < jb.K) ? jb.in[(long)k * jb.D + d] : 0.f;
    } else {
        int o = idx >> 7, j = idx & 127;
        if (j < 105) {
            int k = j / 21, c = j - k * 21;
            v = jb.in[o * 105 + c * 5 + k];
        } else v = 0.f;
    }
    jb.out[idx] = (_Float16)v;
}

// compound_x f32 [2560][78] -> f16 [2560][128] zero-padded (K%64==0 for GEMM)
__global__ void cx_conv_kernel(const float* __restrict__ in, _Float16* __restrict__ out) {
    int i = blockIdx.x * 256 + threadIdx.x;
    if (i >= NC_TOT * 128) return;
    int r = i >> 7, k = i & 127;
    out[i] = (_Float16)(k < 78 ? in[r * 78 + k] : 0.f);
}

// ---------------------------------------------------------------------------
// im2col for conv1d(k=5, pad=2, Cin=21): row i -> [128] f16, j = k*21+c
// ---------------------------------------------------------------------------
__global__ __launch_bounds__(256) void im2col_kernel(
    const float* __restrict__ seq, const int* __restrict__ gather,
    _Float16* __restrict__ out)
{
    int t4 = blockIdx.x * 256 + threadIdx.x;   // one f16x4 group
    int i = t4 >> 5;                           // 32 groups per row
    if (i >= NP_TOT) return;
    int j0 = (t4 & 31) * 4;
    int g = gather[i];
    int bb = g >> 10, l = g & (LMAX - 1);
    f16x4 o;
    #pragma unroll
    for (int u = 0; u < 4; ++u) {
        int j = j0 + u;
        float v = 0.f;
        if (j < 105) {
            int k = j / 21, c = j - k * 21;
            int ll = l + k - 2;
            if ((unsigned)ll < (unsigned)LMAX)
                v = seq[((long)bb * LMAX + ll) * 21 + c];
        }
        o[u] = (_Float16)v;
    }
    *(f16x4*)(out + (long)i * 128 + j0) = o;
}

// ---------------------------------------------------------------------------
// fused dual MFMA GEMM (fp16 in, f32 accum, fp16 out):
//   Out = act(A0 @ W0 [+ A1 @ W1 if npass==2] + bias)
// 128x128 tile, BK=64, double-buffered LDS -> ONE barrier per K-step.
// 256 threads = 4 waves (2x2), 4x4 16x16x32 frags/wave, 32 MFMA/step.
// 8-slot XOR swizzle (slot = chunk ^ (row&7)) -> conflict-free b128 r/w.
// 1-D grid, column-fastest linearization + bijective XCD chunk swizzle so
// column-blocks sharing an A-panel run adjacently (L2 reuse).
// Requires N%128==0, D%128==0, K%64==0.
// ---------------------------------------------------------------------------
__global__ __launch_bounds__(256) void gemm_f16_kernel(
    const _Float16* __restrict__ A0, const _Float16* __restrict__ WT0,
    const _Float16* __restrict__ A1, const _Float16* __restrict__ WT1,
    const float* __restrict__ bias, _Float16* __restrict__ Out,
    int N, int K, int D, int npass, int act)
{
    __shared__ _Float16 Asm[2][128 * 64];
    __shared__ _Float16 Bsm[2][128 * 64];
    const int tid = threadIdx.x;
    const int wave = tid >> 6, lane = tid & 63;
    const int wr = wave >> 1, wc = wave & 1;
    const int l15 = lane & 15, lk = lane >> 4;

    // bijective XCD chunk swizzle (m204) + column-fastest (row, col) decode
    const int nwg = gridDim.x;
    const int bid = blockIdx.x;
    const int q = nwg >> 3, r8 = nwg & 7;
    const int xcd = bid & 7, sl = bid >> 3;
    const int wg = (xcd < r8) ? (xcd * (q + 1) + sl)
                              : (r8 * (q + 1) + (xcd - r8) * q + sl);
    const int DC = D >> 7;
    const long r0 = (long)(wg / DC) * 128;
    const long c0 = (long)(wg % DC) * 128;

    // staging: row = tid>>1 (0..127), half = tid&1 -> 16B chunks half*4..half*4+3
    const int srow = tid >> 1, shalf = tid & 1;
    int wofs[4];
    #pragma unroll
    for (int j = 0; j < 4; ++j) {
        int c = shalf * 4 + j;
        wofs[j] = srow * 64 + ((c ^ (srow & 7)) * 8);
    }

    // fragment read offsets: row = wr*64+m*16+l15, chunk = kk*4+lk
    int aoff[4][2], boff[4][2];
    #pragma unroll
    for (int m = 0; m < 4; ++m) {
        int row = wr * 64 + m * 16 + l15;
        int col = wc * 64 + m * 16 + l15;
        #pragma unroll
        for (int kk = 0; kk < 2; ++kk) {
            aoff[m][kk] = row * 64 + (((kk * 4 + lk) ^ (row & 7)) * 8);
            boff[m][kk] = col * 64 + (((kk * 4 + lk) ^ (col & 7)) * 8);
        }
    }

    f32x4 acc[4][4];
    #pragma unroll
    for (int m = 0; m < 4; ++m)
        #pragma unroll
        for (int n = 0; n < 4; ++n)
            #pragma unroll
            for (int i = 0; i < 4; ++i) acc[m][n][i] = 0.f;

    const int ksteps = K >> 6;
    const int S = ksteps * npass;

    f16x8 ha[4], hb[4];
    auto LOADT = [&](int st) {
        int pass = (st >= ksteps) ? 1 : 0;
        long kb0 = (long)(st - pass * ksteps) * 64;
        const _Float16* Ax = pass ? A1 : A0;
        const _Float16* Wx = pass ? WT1 : WT0;
        #pragma unroll
        for (int j = 0; j < 4; ++j) {
            long kb = kb0 + (shalf * 4 + j) * 8;
            ha[j] = *(const f16x8*)(Ax + (r0 + srow) * K + kb);
            hb[j] = *(const f16x8*)(Wx + (c0 + srow) * K + kb);
        }
    };

    // prologue: tile0 -> buf0; tile1 -> held regs
    LOADT(0);
    #pragma unroll
    for (int j = 0; j < 4; ++j) {
        *(f16x8*)(&Asm[0][0] + wofs[j]) = ha[j];
        *(f16x8*)(&Bsm[0][0] + wofs[j]) = hb[j];
    }
    if (S > 1) LOADT(1);
    __syncthreads();

    for (int s = 0; s < S; ++s) {
        int cur = s & 1, nxt = cur ^ 1;
        if (s + 1 < S) {                      // write held tile s+1 -> other buffer
            #pragma unroll
            for (int j = 0; j < 4; ++j) {
                *(f16x8*)(&Asm[nxt][0] + wofs[j]) = ha[j];
                *(f16x8*)(&Bsm[nxt][0] + wofs[j]) = hb[j];
            }
        }
        if (s + 2 < S) LOADT(s + 2);          // issue loads for s+2 (spans a full step)
        const _Float16* As = &Asm[cur][0];
        const _Float16* Bs = &Bsm[cur][0];
        #pragma unroll
        for (int kk = 0; kk < 2; ++kk) {
            f16x8 af[4], bf[4];
            #pragma unroll
            for (int m = 0; m < 4; ++m) af[m] = *(const f16x8*)(As + aoff[m][kk]);
            #pragma unroll
            for (int n = 0; n < 4; ++n) bf[n] = *(const f16x8*)(Bs + boff[n][kk]);
            #pragma unroll
            for (int m = 0; m < 4; ++m)
                #pragma unroll
                for (int n = 0; n < 4; ++n)
                    acc[m][n] = __builtin_amdgcn_mfma_f32_16x16x32_f16(af[m], bf[n], acc[m][n], 0, 0, 0);
        }
        __syncthreads();                      // single barrier per step
    }

    // epilogue: bias + act + fp16 store
    float bn[4]; int coln[4];
    #pragma unroll
    for (int n = 0; n < 4; ++n) {
        coln[n] = (int)c0 + wc * 64 + n * 16 + l15;
        bn[n] = bias[coln[n]];
    }
    #pragma unroll
    for (int m = 0; m < 4; ++m) {
        long rowb = r0 + wr * 64 + m * 16 + lk * 4;
        #pragma unroll
        for (int i = 0; i < 4; ++i) {
            long row = rowb + i;
            #pragma unroll
            for (int n = 0; n < 4; ++n) {
                float v = acc[m][n][i] + bn[n];
                if (act) v = v > 0.f ? v : 0.01f * v;
                Out[row * D + coln[n]] = (_Float16)v;
            }
        }
    }
}

// ---------------------------------------------------------------------------
// CSR aggregation, latency-optimized: f16x8 lanes + chunk-of-4 index prefetch.
// ---------------------------------------------------------------------------
template<int D>
__global__ __launch_bounds__(256) void agg_f16x8_kernel(
    const _Float16* __restrict__ x, const int* __restrict__ rowptr,
    const int* __restrict__ csr, _Float16* __restrict__ agg, int n)
{
    constexpr int LPN = D / 8;                 // 32 (D=256) or 16 (D=128)
    int node = (blockIdx.x * 256 + threadIdx.x) / LPN;
    int lane = threadIdx.x & (LPN - 1);
    if (node >= n) return;
    int beg = rowptr[node], end = rowptr[node + 1];
    float acc[8] = {};
    const long lo = lane * 8;
    for (int j = beg; j < end; j += 4) {
        int r = end - j;
        int s0 = csr[j];
        int s1 = (r > 1) ? csr[j + 1] : s0;
        int s2 = (r > 2) ? csr[j + 2] : s0;
        int s3 = (r > 3) ? csr[j + 3] : s0;
        f16x8 v0 = *(const f16x8*)(x + (long)s0 * D + lo);
        f16x8 v1 = *(const f16x8*)(x + (long)s1 * D + lo);
        f16x8 v2 = *(const f16x8*)(x + (long)s2 * D + lo);
        f16x8 v3 = *(const f16x8*)(x + (long)s3 * D + lo);
        #pragma unroll
        for (int u = 0; u < 8; ++u) acc[u] += (float)v0[u];
        if (r > 1) {
            #pragma unroll
            for (int u = 0; u < 8; ++u) acc[u] += (float)v1[u];
        }
        if (r > 2) {
            #pragma unroll
            for (int u = 0; u < 8; ++u) acc[u] += (float)v2[u];
        }
        if (r > 3) {
            #pragma unroll
            for (int u = 0; u < 8; ++u) acc[u] += (float)v3[u];
        }
    }
    f16x8 o;
    #pragma unroll
    for (int u = 0; u < 8; ++u) o[u] = (_Float16)acc[u];
    *(f16x8*)(agg + (long)node * D + lo) = o;
}

// ---------------------------------------------------------------------------
// pooling, vectorized f16x8 (16B/lane coalesced)
// ---------------------------------------------------------------------------
__global__ __launch_bounds__(256) void pool_comp_kernel(
    const _Float16* __restrict__ x, float* __restrict__ out)
{
    __shared__ float sm[4][512];
    int g = blockIdx.x;
    int cg = threadIdx.x & 63, rs = threadIdx.x >> 6;
    float m[8];
    #pragma unroll
    for (int u = 0; u < 8; ++u) m[u] = -INFINITY;
    for (int r = rs; r < 40; r += 4) {
        f16x8 v = *(const f16x8*)(x + (long)(g * 40 + r) * 512 + cg * 8);
        #pragma unroll
        for (int u = 0; u < 8; ++u) m[u] = fmaxf(m[u], (float)v[u]);
    }
    #pragma unroll
    for (int u = 0; u < 8; ++u) sm[rs][cg * 8 + u] = m[u];
    __syncthreads();
    if (rs == 0) {
        #pragma unroll
        for (int u = 0; u < 8; ++u) {
            int c = cg * 8 + u;
            out[g * 512 + c] = fmaxf(fmaxf(sm[0][c], sm[1][c]), fmaxf(sm[2][c], sm[3][c]));
        }
    }
}

#define PSPLIT 8
#define PPART  (PSPLIT * 4)   // 32 partials per graph
__global__ __launch_bounds__(256) void pool_prot_partial_kernel(
    const _Float16* __restrict__ x, float* __restrict__ part)
{
    int g = blockIdx.x, s = blockIdx.y;
    int cg = threadIdx.x & 63, rs = threadIdx.x >> 6;
    int start = 512 * ((g + 1) / 2) + 1024 * (g / 2);
    int len = (g & 1) ? 1024 : 512;
    int chunk = len / PSPLIT;     // 64 or 128
    int sub = chunk >> 2;         // 16 or 32 rows per thread
    long r0 = start + s * chunk + rs * sub;
    float m[8];
    #pragma unroll
    for (int u = 0; u < 8; ++u) m[u] = -INFINITY;
    for (int r = 0; r < sub; ++r) {
        f16x8 v = *(const f16x8*)(x + (r0 + r) * 512 + cg * 8);
        #pragma unroll
        for (int u = 0; u < 8; ++u) m[u] = fmaxf(m[u], (float)v[u]);
    }
    float* o = part + (long)((g * PSPLIT + s) * 4 + rs) * 512 + cg * 8;
    #pragma unroll
    for (int u = 0; u < 8; ++u) o[u] = m[u];
}

__global__ __launch_bounds__(256) void pool_prot_final_kernel(
    const float* __restrict__ part, float* __restrict__ out)
{
    int g = blockIdx.x;
    int col = blockIdx.y * 256 + threadIdx.x;
    float m = -INFINITY;
    #pragma unroll 8
    for (int p = 0; p < PPART; ++p)
        m = fmaxf(m, part[(long)(g * PPART + p) * 512 + col]);
    out[g * 512 + col] = m;
}

// ---------------------------------------------------------------------------
// head: cfc/pfc -> concat -> fc1 -> out   (one block per graph, f32)
// ---------------------------------------------------------------------------
__global__ __launch_bounds__(256) void head_kernel(
    const float* __restrict__ cpool, const float* __restrict__ ppool,
    const float* __restrict__ cfc_w, const float* __restrict__ cfc_b,
    const float* __restrict__ pfc_w, const float* __restrict__ pfc_b,
    const float* __restrict__ fc1_w, const float* __restrict__ fc1_b,
    const float* __restrict__ out_w, const float* __restrict__ out_b,
    float* __restrict__ out)
{
    __shared__ float cp[512], pp[512], cf[128], pf[128], h[256], red[256];
    int g = blockIdx.x, t = threadIdx.x;
    for (int i = t; i < 512; i += 256) {
        cp[i] = cpool[g * 512 + i];
        pp[i] = ppool[g * 512 + i];
    }
    __syncthreads();
    if (t < 128) {
        float a = cfc_b[t];
        for (int k = 0; k < 512; k++) a += cp[k] * cfc_w[k * 128 + t];
        cf[t] = lrelu(a);
    } else {
        int o = t - 128;
        float a = pfc_b[o];
        for (int k = 0; k < 512; k++) a += pp[k] * pfc_w[k * 128 + o];
        pf[o] = lrelu(a);
    }
    __syncthreads();
    {
        float a = fc1_b[t];
        for (int k = 0; k < 128; k++) a += cf[k] * fc1_w[k * 256 + t];
        for (int k = 0; k < 128; k++) a += pf[k] * fc1_w[(128 + k) * 256 + t];
        h[t] = lrelu(a);
    }
    __syncthreads();
    red[t] = h[t] * out_w[t];
    __syncthreads();
    for (int s = 128; s > 0; s >>= 1) {
        if (t < s) red[t] += red[t + s];
        __syncthreads();
    }
    if (t == 0) out[g] = red[0] + out_b[0];
}

// ---------------------------------------------------------------------------
// launch
// ---------------------------------------------------------------------------
extern "C" void kernel_launch(void* const* d_in, const int* in_sizes, int n_in,
                              void* d_out, int out_size, void* d_ws, size_t ws_size,
                              hipStream_t stream) {
    const float* seq_x      = (const float*)d_in[0];
    const float* compound_x = (const float*)d_in[1];
    const float* conv_w     = (const float*)d_in[2];
    const float* conv_b     = (const float*)d_in[3];
    const float* c1_wl = (const float*)d_in[4];
    const float* c1_bl = (const float*)d_in[5];
    const float* c1_wr = (const float*)d_in[6];
    const float* c2_wl = (const float*)d_in[7];
    const float* c2_bl = (const float*)d_in[8];
    const float* c2_wr = (const float*)d_in[9];
    const float* c3_wl = (const float*)d_in[10];
    const float* c3_bl = (const float*)d_in[11];
    const float* c3_wr = (const float*)d_in[12];
    const float* cfc_w = (const float*)d_in[13];
    const float* cfc_b = (const float*)d_in[14];
    const float* p1_wl = (const float*)d_in[15];
    const float* p1_bl = (const float*)d_in[16];
    const float* p1_wr = (const float*)d_in[17];
    const float* p2_wl = (const float*)d_in[18];
    const float* p2_bl = (const float*)d_in[19];
    const float* p2_wr = (const float*)d_in[20];
    const float* p3_wl = (const float*)d_in[21];
    const float* p3_bl = (const float*)d_in[22];
    const float* p3_wr = (const float*)d_in[23];
    const float* pfc_w = (const float*)d_in[24];
    const float* pfc_b = (const float*)d_in[25];
    const float* fc1_w = (const float*)d_in[26];
    const float* fc1_b = (const float*)d_in[27];
    const float* out_w = (const float*)d_in[28];
    const float* out_b = (const float*)d_in[29];
    const int* prot_gather = (const int*)d_in[30];
    const int* prot_src    = (const int*)d_in[31];
    const int* prot_tgt    = (const int*)d_in[32];
    const int* comp_src    = (const int*)d_in[33];
    const int* comp_tgt    = (const int*)d_in[34];

    float* out = (float*)d_out;

    // workspace layout
    size_t off = 0;
    auto alloc = [&](size_t bytes) -> char* {
        char* p = (char*)d_ws + off;
        off = (off + bytes + 255) & ~(size_t)255;
        return p;
    };
    // fp16 activation buffers
    _Float16* pim   = (_Float16*)alloc((size_t)NP_TOT * 128 * 2);   // im2col
    _Float16* pconv = (_Float16*)alloc((size_t)NP_TOT * 128 * 2);
    _Float16* pagg  = (_Float16*)alloc((size_t)NP_TOT * 256 * 2);
    _Float16* pl1   = (_Float16*)alloc((size_t)NP_TOT * 128 * 2);
    _Float16* pl2   = (_Float16*)alloc((size_t)NP_TOT * 256 * 2);
    _Float16* pl3   = (_Float16*)alloc((size_t)NP_TOT * 512 * 2);
    _Float16* cxp   = (_Float16*)alloc((size_t)NC_TOT * 128 * 2);   // padded to 128
    _Float16* cagg  = (_Float16*)alloc((size_t)NC_TOT * 256 * 2);
    _Float16* cl1   = (_Float16*)alloc((size_t)NC_TOT * 128 * 2);
    _Float16* cl2   = (_Float16*)alloc((size_t)NC_TOT * 256 * 2);
    _Float16* cl3   = (_Float16*)alloc((size_t)NC_TOT * 512 * 2);
    // fp16 transposed weights [D][Kp]
    _Float16* wt_p1l = (_Float16*)alloc(128 * 128 * 2);
    _Float16* wt_p1r = (_Float16*)alloc(128 * 128 * 2);
    _Float16* wt_p2l = (_Float16*)alloc(256 * 128 * 2);
    _Float16* wt_p2r = (_Float16*)alloc(256 * 128 * 2);
    _Float16* wt_p3l = (_Float16*)alloc(512 * 256 * 2);
    _Float16* wt_p3r = (_Float16*)alloc(512 * 256 * 2);
    _Float16* wt_c1l = (_Float16*)alloc(128 * 128 * 2);             // Kp=128
    _Float16* wt_c1r = (_Float16*)alloc(128 * 128 * 2);
    _Float16* wt_c2l = (_Float16*)alloc(256 * 128 * 2);
    _Float16* wt_c2r = (_Float16*)alloc(256 * 128 * 2);
    _Float16* wt_c3l = (_Float16*)alloc(512 * 256 * 2);
    _Float16* wt_c3r = (_Float16*)alloc(512 * 256 * 2);
    _Float16* wt_cv  = (_Float16*)alloc(128 * 128 * 2);
    // pools (f32)
    float* cpool = (float*)alloc(B_GRAPHS * 512 * 4);
    float* ppool = (float*)alloc(B_GRAPHS * 512 * 4);
    float* ppart = (float*)alloc((size_t)B_GRAPHS * PPART * 512 * 4);
    // CSR (cursors contiguous so one zero pass covers both)
    int* cursors  = (int*)alloc((NP_TOT + NC_TOT) * 4);
    int* p_cursor = cursors;
    int* c_cursor = cursors + NP_TOT;
    int* p_rowptr = (int*)alloc((NP_TOT + 1) * 4);
    int* p_csr    = (int*)alloc(EP_TOT * 4);
    int* c_rowptr = (int*)alloc((NC_TOT + 1) * 4);
    int* c_csr    = (int*)alloc(EC_TOT * 4);
    int* bsums    = (int*)alloc(SCAN_NB * 4);
    (void)ws_size; (void)n_in; (void)in_sizes; (void)out_size;

    // ---- weight prep (one launch) + compound input conversion ----
    WJobs jobs;
    jobs.j[0]  = { p1_wl, wt_p1l, 128, 128, 128, 0 };
    jobs.j[1]  = { p1_wr, wt_p1r, 128, 128, 128, 0 };
    jobs.j[2]  = { p2_wl, wt_p2l, 128, 256, 128, 0 };
    jobs.j[3]  = { p2_wr, wt_p2r, 128, 256, 128, 0 };
    jobs.j[4]  = { p3_wl, wt_p3l, 256, 512, 256, 0 };
    jobs.j[5]  = { p3_wr, wt_p3r, 256, 512, 256, 0 };
    jobs.j[6]  = { c1_wl, wt_c1l,  78, 128, 128, 0 };
    jobs.j[7]  = { c1_wr, wt_c1r,  78, 128, 128, 0 };
    jobs.j[8]  = { c2_wl, wt_c2l, 128, 256, 128, 0 };
    jobs.j[9]  = { c2_wr, wt_c2r, 128, 256, 128, 0 };
    jobs.j[10] = { c3_wl, wt_c3l, 256, 512, 256, 0 };
    jobs.j[11] = { c3_wr, wt_c3r, 256, 512, 256, 0 };
    jobs.j[12] = { conv_w, wt_cv, 105, 128, 128, 1 };
    wprep_all_kernel<<<dim3(512, 1, 13), 256, 0, stream>>>(jobs);
    cx_conv_kernel<<<(NC_TOT * 128 + 255) / 256, 256, 0, stream>>>(compound_x, cxp);

    // ---- CSR build (both graphs, fused; parallel scan) ----
    zero_int_kernel<<<(SCAN_N + 255) / 256, 256, 0, stream>>>(cursors, SCAN_N);
    hist2_kernel<<<(EP_TOT + EC_TOT + 255) / 256, 256, 0, stream>>>(prot_tgt, p_cursor, comp_tgt, c_cursor);
    scan_bsum_kernel<<<SCAN_NB, 256, 0, stream>>>(cursors, bsums);
    scan_sums_kernel<<<1, 128, 0, stream>>>(bsums);
    scan_final_kernel<<<SCAN_NB, 256, 0, stream>>>(cursors, bsums, p_rowptr, c_rowptr);
    zero_int_kernel<<<(SCAN_N + 255) / 256, 256, 0, stream>>>(cursors, SCAN_N);
    scatter2_kernel<<<(EP_TOT + EC_TOT + 255) / 256, 256, 0, stream>>>(
        prot_src, prot_tgt, p_rowptr, p_cursor, p_csr,
        comp_src, comp_tgt, c_rowptr, c_cursor, c_csr);

    // ---- conv as im2col + MFMA GEMM -> pconv [NP,128] f16 (no activation) ----
    im2col_kernel<<<(NP_TOT * 32 + 255) / 256, 256, 0, stream>>>(seq_x, prot_gather, pim);
    gemm_f16_kernel<<<NP_TOT / 128, 256, 0, stream>>>(
        pim, wt_cv, pim, wt_cv, conv_b, pconv, NP_TOT, 128, 128, 1, 0);

    // ---- compound GNN ----
    agg_f16x8_kernel<128><<<(NC_TOT * 16 + 255) / 256, 256, 0, stream>>>(cxp, c_rowptr, c_csr, cagg, NC_TOT);
    gemm_f16_kernel<<<NC_TOT / 128, 256, 0, stream>>>(
        cagg, wt_c1l, cxp, wt_c1r, c1_bl, cl1, NC_TOT, 128, 128, 2, 1);
    agg_f16x8_kernel<128><<<(NC_TOT * 16 + 255) / 256, 256, 0, stream>>>(cl1, c_rowptr, c_csr, cagg, NC_TOT);
    gemm_f16_kernel<<<(NC_TOT / 128) * 2, 256, 0, stream>>>(
        cagg, wt_c2l, cl1, wt_c2r, c2_bl, cl2, NC_TOT, 128, 256, 2, 1);
    agg_f16x8_kernel<256><<<(NC_TOT * 32 + 255) / 256, 256, 0, stream>>>(cl2, c_rowptr, c_csr, cagg, NC_TOT);
    gemm_f16_kernel<<<(NC_TOT / 128) * 4, 256, 0, stream>>>(
        cagg, wt_c3l, cl2, wt_c3r, c3_bl, cl3, NC_TOT, 256, 512, 2, 1);
    pool_comp_kernel<<<B_GRAPHS, 256, 0, stream>>>(cl3, cpool);

    // ---- protein GNN ----
    agg_f16x8_kernel<128><<<(NP_TOT * 16 + 255) / 256, 256, 0, stream>>>(pconv, p_rowptr, p_csr, pagg, NP_TOT);
    gemm_f16_kernel<<<NP_TOT / 128, 256, 0, stream>>>(
        pagg, wt_p1l, pconv, wt_p1r, p1_bl, pl1, NP_TOT, 128, 128, 2, 1);
    agg_f16x8_kernel<128><<<(NP_TOT * 16 + 255) / 256, 256, 0, stream>>>(pl1, p_rowptr, p_csr, pagg, NP_TOT);
    gemm_f16_kernel<<<(NP_TOT / 128) * 2, 256, 0, stream>>>(
        pagg, wt_p2l, pl1, wt_p2r, p2_bl, pl2, NP_TOT, 128, 256, 2, 1);
    agg_f16x8_kernel<256><<<(NP_TOT * 32 + 255) / 256, 256, 0, stream>>>(pl2, p_rowptr, p_csr, pagg, NP_TOT);
    gemm_f16_kernel<<<(NP_TOT / 128) * 4, 256, 0, stream>>>(
        pagg, wt_p3l, pl2, wt_p3r, p3_bl, pl3, NP_TOT, 256, 512, 2, 1);
    pool_prot_partial_kernel<<<dim3(B_GRAPHS, PSPLIT), 256, 0, stream>>>(pl3, ppart);
    pool_prot_final_kernel<<<dim3(B_GRAPHS, 2), 256, 0, stream>>>(ppart, ppool);

    // ---- head ----
    head_kernel<<<B_GRAPHS, 256, 0, stream>>>(cpool, ppool, cfc_w, cfc_b, pfc_w, pfc_b,
                                              fc1_w, fc1_b, out_w, out_b, out);
}

// Round 15
// 367.228 us; speedup vs baseline: 1.1041x; 1.1041x over previous
//
#include <hip/hip_runtime.h>
#include <hip/hip_fp16.h>

// ---------------------------------------------------------------------------
// Problem constants (from reference)
// ---------------------------------------------------------------------------
#define B_GRAPHS 64
#define LMAX 1024
#define NP_TOT 49152      // sum(LENS)
#define NC_TOT 2560       // 64*40
#define EP_TOT 393216     // 8 * NP
#define EC_TOT 10240      // 4 * NC

#define SCAN_N   (NP_TOT + NC_TOT)   // 51712
#define SCAN_BLK 512
#define SCAN_NB  (SCAN_N / SCAN_BLK) // 101 (exact)

typedef _Float16 f16x8 __attribute__((ext_vector_type(8)));
typedef _Float16 f16x4 __attribute__((ext_vector_type(4)));
typedef _Float16 f16x2 __attribute__((ext_vector_type(2)));
typedef float    f32x4 __attribute__((ext_vector_type(4)));

__device__ __forceinline__ float lrelu(float x) { return x > 0.f ? x : 0.01f * x; }

// ---------------------------------------------------------------------------
// CSR build (fused, both graphs)
// ---------------------------------------------------------------------------
__global__ void zero_int_kernel(int* p, int n) {
    int i = blockIdx.x * blockDim.x + threadIdx.x;
    if (i < n) p[i] = 0;
}

__global__ void hist2_kernel(const int* __restrict__ ptgt, int* __restrict__ pdeg,
                             const int* __restrict__ ctgt, int* __restrict__ cdeg) {
    int e = blockIdx.x * blockDim.x + threadIdx.x;
    if (e < EP_TOT) atomicAdd(&pdeg[ptgt[e]], 1);
    else if (e < EP_TOT + EC_TOT) atomicAdd(&cdeg[ctgt[e - EP_TOT]], 1);
}

// ---- parallel exclusive scan over the concatenated degree array ----
__global__ __launch_bounds__(256) void scan_bsum_kernel(
    const int* __restrict__ deg, int* __restrict__ bsums)
{
    __shared__ int red[256];
    int b = blockIdx.x, t = threadIdx.x;
    int2 e = *(const int2*)(deg + b * SCAN_BLK + t * 2);
    red[t] = e.x + e.y;
    __syncthreads();
    for (int s = 128; s > 0; s >>= 1) {
        if (t < s) red[t] += red[t + s];
        __syncthreads();
    }
    if (t == 0) bsums[b] = red[0];
}

__global__ __launch_bounds__(128) void scan_sums_kernel(int* __restrict__ bsums)
{
    __shared__ int v[SCAN_NB];
    int t = threadIdx.x;
    if (t < SCAN_NB) v[t] = bsums[t];
    __syncthreads();
    if (t == 0) {
        int run = 0;
        for (int i = 0; i < SCAN_NB; ++i) { int x = v[i]; v[i] = run; run += x; }
    }
    __syncthreads();
    if (t < SCAN_NB) bsums[t] = v[t];
}

__global__ __launch_bounds__(256) void scan_final_kernel(
    const int* __restrict__ deg, const int* __restrict__ bsums,
    int* __restrict__ p_rowptr, int* __restrict__ c_rowptr)
{
    __shared__ int wsum[4];
    int b = blockIdx.x, t = threadIdx.x;
    int i = b * SCAN_BLK + t * 2;
    int2 e = *(const int2*)(deg + i);
    int ts = e.x + e.y;
    int lane = t & 63, wv = t >> 6;
    int x = ts;
    #pragma unroll
    for (int o = 1; o < 64; o <<= 1) {
        int y = __shfl_up(x, o);
        if (lane >= o) x += y;
    }
    if (lane == 63) wsum[wv] = x;
    __syncthreads();
    int base = bsums[b];
    for (int w = 0; w < wv; ++w) base += wsum[w];
    int excl = base + x - ts;
    int v0 = excl, v1 = excl + e.x;
    if (i < NP_TOT) p_rowptr[i] = v0; else c_rowptr[i - NP_TOT] = v0 - EP_TOT;
    if (i + 1 < NP_TOT) p_rowptr[i + 1] = v1; else c_rowptr[i + 1 - NP_TOT] = v1 - EP_TOT;
    if (b == 0 && t == 0) { p_rowptr[NP_TOT] = EP_TOT; c_rowptr[NC_TOT] = EC_TOT; }
}

__global__ void scatter2_kernel(const int* __restrict__ ps, const int* __restrict__ pt,
                                const int* __restrict__ prow, int* __restrict__ pcur,
                                int* __restrict__ pcsr,
                                const int* __restrict__ cs, const int* __restrict__ ct,
                                const int* __restrict__ crow, int* __restrict__ ccur,
                                int* __restrict__ ccsr) {
    int e = blockIdx.x * blockDim.x + threadIdx.x;
    if (e < EP_TOT) {
        int t = pt[e];
        int pos = atomicAdd(&pcur[t], 1);
        pcsr[prow[t] + pos] = ps[e];
    } else if (e < EP_TOT + EC_TOT) {
        int e2 = e - EP_TOT;
        int t = ct[e2];
        int pos = atomicAdd(&ccur[t], 1);
        ccsr[crow[t] + pos] = cs[e2];
    }
}

// ---------------------------------------------------------------------------
// fused weight prep: 13 jobs in one launch (blockIdx.z selects)
// ---------------------------------------------------------------------------
struct WJob { const float* in; _Float16* out; int K, D, Kp, mode; };
struct WJobs { WJob j[13]; };

__global__ __launch_bounds__(256) void wprep_all_kernel(WJobs jobs) {
    WJob jb = jobs.j[blockIdx.z];
    int idx = blockIdx.x * 256 + threadIdx.x;
    int total = jb.D * jb.Kp;
    if (idx >= total) return;
    float v;
    if (jb.mode == 0) {
        int d = idx / jb.Kp, k = idx - d * jb.Kp;
        v = (k < jb.K) ? jb.in[(long)k * jb.D + d] : 0.f;
    } else {
        int o = idx >> 7, j = idx & 127;
        if (j < 105) {
            int k = j / 21, c = j - k * 21;
            v = jb.in[o * 105 + c * 5 + k];
        } else v = 0.f;
    }
    jb.out[idx] = (_Float16)v;
}

// compound_x f32 [2560][78] -> f16 [2560][128] zero-padded (K%64==0 for GEMM)
__global__ void cx_conv_kernel(const float* __restrict__ in, _Float16* __restrict__ out) {
    int i = blockIdx.x * 256 + threadIdx.x;
    if (i >= NC_TOT * 128) return;
    int r = i >> 7, k = i & 127;
    out[i] = (_Float16)(k < 78 ? in[r * 78 + k] : 0.f);
}

// ---------------------------------------------------------------------------
// im2col for conv1d(k=5, pad=2, Cin=21): row i -> [128] f16, j = k*21+c
// ---------------------------------------------------------------------------
__global__ __launch_bounds__(256) void im2col_kernel(
    const float* __restrict__ seq, const int* __restrict__ gather,
    _Float16* __restrict__ out)
{
    int t4 = blockIdx.x * 256 + threadIdx.x;   // one f16x4 group
    int i = t4 >> 5;                           // 32 groups per row
    if (i >= NP_TOT) return;
    int j0 = (t4 & 31) * 4;
    int g = gather[i];
    int bb = g >> 10, l = g & (LMAX - 1);
    f16x4 o;
    #pragma unroll
    for (int u = 0; u < 4; ++u) {
        int j = j0 + u;
        float v = 0.f;
        if (j < 105) {
            int k = j / 21, c = j - k * 21;
            int ll = l + k - 2;
            if ((unsigned)ll < (unsigned)LMAX)
                v = seq[((long)bb * LMAX + ll) * 21 + c];
        }
        o[u] = (_Float16)v;
    }
    *(f16x4*)(out + (long)i * 128 + j0) = o;
}

// ---------------------------------------------------------------------------
// fused dual MFMA GEMM (fp16 in, f32 accum, fp16 out), dual-JOB launch:
// grid covers job P then job C (identical K,D; different N/pointers).
// 128x128 tile, BK=64, single-buffered LDS (32 KB -> high occupancy),
// 256 threads = 4 waves (2x2), 4x4 16x16x32 frags/wave, 32 MFMA per 2
// barriers. 8-slot XOR swizzle -> conflict-free b128 r/w. Column-fastest
// 1-D decode + bijective XCD chunk swizzle within each job (L2 A-reuse).
// Requires N%128==0, D%128==0, K%64==0.
// ---------------------------------------------------------------------------
struct GemmJob {
    const _Float16* A0; const _Float16* WT0;
    const _Float16* A1; const _Float16* WT1;
    const float* bias; _Float16* Out;
    int N, K, D, npass, act, nwg;
};

__global__ __launch_bounds__(256) void gemm_f16_kernel(GemmJob jp, GemmJob jc)
{
    __shared__ _Float16 Asm[128 * 64];
    __shared__ _Float16 Bsm[128 * 64];
    const int tid = threadIdx.x;
    const int wave = tid >> 6, lane = tid & 63;
    const int wr = wave >> 1, wc = wave & 1;
    const int l15 = lane & 15, lk = lane >> 4;

    const int bid = blockIdx.x;
    const GemmJob& j = (bid < jp.nwg) ? jp : jc;
    const int lb = (bid < jp.nwg) ? bid : bid - jp.nwg;
    const int K = j.K, D = j.D;

    // bijective XCD chunk swizzle (m204) within this job's sub-grid
    const int nwg = j.nwg;
    const int q = nwg >> 3, r8 = nwg & 7;
    const int xcd = lb & 7, sl = lb >> 3;
    const int wg = (xcd < r8) ? (xcd * (q + 1) + sl)
                              : (r8 * (q + 1) + (xcd - r8) * q + sl);
    const int DC = D >> 7;
    const long r0 = (long)(wg / DC) * 128;
    const long c0 = (long)(wg % DC) * 128;

    // staging: row = tid>>1 (0..127), half = tid&1 -> 16B chunks half*4..half*4+3
    const int srow = tid >> 1, shalf = tid & 1;
    int wofs[4];
    #pragma unroll
    for (int jj = 0; jj < 4; ++jj) {
        int c = shalf * 4 + jj;
        wofs[jj] = srow * 64 + ((c ^ (srow & 7)) * 8);
    }

    // fragment read offsets: row = wr*64+m*16+l15, chunk = kk*4+lk
    int aoff[4][2], boff[4][2];
    #pragma unroll
    for (int m = 0; m < 4; ++m) {
        int row = wr * 64 + m * 16 + l15;
        int col = wc * 64 + m * 16 + l15;
        #pragma unroll
        for (int kk = 0; kk < 2; ++kk) {
            aoff[m][kk] = row * 64 + (((kk * 4 + lk) ^ (row & 7)) * 8);
            boff[m][kk] = col * 64 + (((kk * 4 + lk) ^ (col & 7)) * 8);
        }
    }

    f32x4 acc[4][4];
    #pragma unroll
    for (int m = 0; m < 4; ++m)
        #pragma unroll
        for (int n = 0; n < 4; ++n)
            #pragma unroll
            for (int i = 0; i < 4; ++i) acc[m][n][i] = 0.f;

    const int ksteps = K >> 6;
    const int S = ksteps * j.npass;

    // prologue: load step 0
    f16x8 av[4], bv[4];
    #pragma unroll
    for (int jj = 0; jj < 4; ++jj) {
        long kb = (long)(shalf * 4 + jj) * 8;
        av[jj] = *(const f16x8*)(j.A0  + (r0 + srow) * K + kb);
        bv[jj] = *(const f16x8*)(j.WT0 + (c0 + srow) * K + kb);
    }

    for (int s = 0; s < S; ++s) {
        __syncthreads();                      // LDS free (prev compute done)
        #pragma unroll
        for (int jj = 0; jj < 4; ++jj) *(f16x8*)(Asm + wofs[jj]) = av[jj];
        #pragma unroll
        for (int jj = 0; jj < 4; ++jj) *(f16x8*)(Bsm + wofs[jj]) = bv[jj];
        __syncthreads();                      // tile ready
        if (s + 1 < S) {                      // prefetch next tile (overlaps MFMA)
            int s1 = s + 1;
            int pass = (s1 >= ksteps) ? 1 : 0;
            long kb0 = (long)(s1 - pass * ksteps) * 64;
            const _Float16* Ax = pass ? j.A1 : j.A0;
            const _Float16* Wx = pass ? j.WT1 : j.WT0;
            #pragma unroll
            for (int jj = 0; jj < 4; ++jj) {
                long kb = kb0 + (shalf * 4 + jj) * 8;
                av[jj] = *(const f16x8*)(Ax + (r0 + srow) * K + kb);
                bv[jj] = *(const f16x8*)(Wx + (c0 + srow) * K + kb);
            }
        }
        #pragma unroll
        for (int kk = 0; kk < 2; ++kk) {
            f16x8 af[4], bf[4];
            #pragma unroll
            for (int m = 0; m < 4; ++m) af[m] = *(const f16x8*)(Asm + aoff[m][kk]);
            #pragma unroll
            for (int n = 0; n < 4; ++n) bf[n] = *(const f16x8*)(Bsm + boff[n][kk]);
            #pragma unroll
            for (int m = 0; m < 4; ++m)
                #pragma unroll
                for (int n = 0; n < 4; ++n)
                    acc[m][n] = __builtin_amdgcn_mfma_f32_16x16x32_f16(af[m], bf[n], acc[m][n], 0, 0, 0);
        }
    }

    // epilogue: bias + act + fp16 store
    float bn[4]; int coln[4];
    #pragma unroll
    for (int n = 0; n < 4; ++n) {
        coln[n] = (int)c0 + wc * 64 + n * 16 + l15;
        bn[n] = j.bias[coln[n]];
    }
    #pragma unroll
    for (int m = 0; m < 4; ++m) {
        long rowb = r0 + wr * 64 + m * 16 + lk * 4;
        #pragma unroll
        for (int i = 0; i < 4; ++i) {
            long row = rowb + i;
            #pragma unroll
            for (int n = 0; n < 4; ++n) {
                float v = acc[m][n][i] + bn[n];
                if (j.act) v = v > 0.f ? v : 0.01f * v;
                j.Out[row * D + coln[n]] = (_Float16)v;
            }
        }
    }
}

// ---------------------------------------------------------------------------
// CSR aggregation, dual-job: f16x8 lanes + chunk-of-4 index prefetch.
// ---------------------------------------------------------------------------
struct AggJob {
    const _Float16* x; const int* rowptr; const int* csr;
    _Float16* agg; int n, nwg;
};

template<int D>
__global__ __launch_bounds__(256) void agg_f16x8_kernel(AggJob ja, AggJob jb)
{
    constexpr int LPN = D / 8;                 // 32 (D=256) or 16 (D=128)
    int bid = blockIdx.x;
    const AggJob& j = (bid < ja.nwg) ? ja : jb;
    int lb = (bid < ja.nwg) ? bid : bid - ja.nwg;
    int node = (lb * 256 + threadIdx.x) / LPN;
    int lane = threadIdx.x & (LPN - 1);
    if (node >= j.n) return;
    int beg = j.rowptr[node], end = j.rowptr[node + 1];
    float acc[8] = {};
    const long lo = lane * 8;
    const _Float16* x = j.x;
    const int* csr = j.csr;
    for (int jj = beg; jj < end; jj += 4) {
        int r = end - jj;
        int s0 = csr[jj];
        int s1 = (r > 1) ? csr[jj + 1] : s0;
        int s2 = (r > 2) ? csr[jj + 2] : s0;
        int s3 = (r > 3) ? csr[jj + 3] : s0;
        f16x8 v0 = *(const f16x8*)(x + (long)s0 * D + lo);
        f16x8 v1 = *(const f16x8*)(x + (long)s1 * D + lo);
        f16x8 v2 = *(const f16x8*)(x + (long)s2 * D + lo);
        f16x8 v3 = *(const f16x8*)(x + (long)s3 * D + lo);
        #pragma unroll
        for (int u = 0; u < 8; ++u) acc[u] += (float)v0[u];
        if (r > 1) {
            #pragma unroll
            for (int u = 0; u < 8; ++u) acc[u] += (float)v1[u];
        }
        if (r > 2) {
            #pragma unroll
            for (int u = 0; u < 8; ++u) acc[u] += (float)v2[u];
        }
        if (r > 3) {
            #pragma unroll
            for (int u = 0; u < 8; ++u) acc[u] += (float)v3[u];
        }
    }
    f16x8 o;
    #pragma unroll
    for (int u = 0; u < 8; ++u) o[u] = (_Float16)acc[u];
    *(f16x8*)(j.agg + (long)node * D + lo) = o;
}

// ---------------------------------------------------------------------------
// pooling, vectorized f16x8 (16B/lane coalesced)
// ---------------------------------------------------------------------------
__global__ __launch_bounds__(256) void pool_comp_kernel(
    const _Float16* __restrict__ x, float* __restrict__ out)
{
    __shared__ float sm[4][512];
    int g = blockIdx.x;
    int cg = threadIdx.x & 63, rs = threadIdx.x >> 6;
    float m[8];
    #pragma unroll
    for (int u = 0; u < 8; ++u) m[u] = -INFINITY;
    for (int r = rs; r < 40; r += 4) {
        f16x8 v = *(const f16x8*)(x + (long)(g * 40 + r) * 512 + cg * 8);
        #pragma unroll
        for (int u = 0; u < 8; ++u) m[u] = fmaxf(m[u], (float)v[u]);
    }
    #pragma unroll
    for (int u = 0; u < 8; ++u) sm[rs][cg * 8 + u] = m[u];
    __syncthreads();
    if (rs == 0) {
        #pragma unroll
        for (int u = 0; u < 8; ++u) {
            int c = cg * 8 + u;
            out[g * 512 + c] = fmaxf(fmaxf(sm[0][c], sm[1][c]), fmaxf(sm[2][c], sm[3][c]));
        }
    }
}

#define PSPLIT 8
#define PPART  (PSPLIT * 4)   // 32 partials per graph
__global__ __launch_bounds__(256) void pool_prot_partial_kernel(
    const _Float16* __restrict__ x, float* __restrict__ part)
{
    int g = blockIdx.x, s = blockIdx.y;
    int cg = threadIdx.x & 63, rs = threadIdx.x >> 6;
    int start = 512 * ((g + 1) / 2) + 1024 * (g / 2);
    int len = (g & 1) ? 1024 : 512;
    int chunk = len / PSPLIT;     // 64 or 128
    int sub = chunk >> 2;         // 16 or 32 rows per thread
    long r0 = start + s * chunk + rs * sub;
    float m[8];
    #pragma unroll
    for (int u = 0; u < 8; ++u) m[u] = -INFINITY;
    for (int r = 0; r < sub; ++r) {
        f16x8 v = *(const f16x8*)(x + (r0 + r) * 512 + cg * 8);
        #pragma unroll
        for (int u = 0; u < 8; ++u) m[u] = fmaxf(m[u], (float)v[u]);
    }
    float* o = part + (long)((g * PSPLIT + s) * 4 + rs) * 512 + cg * 8;
    #pragma unroll
    for (int u = 0; u < 8; ++u) o[u] = m[u];
}

__global__ __launch_bounds__(256) void pool_prot_final_kernel(
    const float* __restrict__ part, float* __restrict__ out)
{
    int g = blockIdx.x;
    int col = blockIdx.y * 256 + threadIdx.x;
    float m = -INFINITY;
    #pragma unroll 8
    for (int p = 0; p < PPART; ++p)
        m = fmaxf(m, part[(long)(g * PPART + p) * 512 + col]);
    out[g * 512 + col] = m;
}

// ---------------------------------------------------------------------------
// head: cfc/pfc -> concat -> fc1 -> out   (one block per graph, f32)
// ---------------------------------------------------------------------------
__global__ __launch_bounds__(256) void head_kernel(
    const float* __restrict__ cpool, const float* __restrict__ ppool,
    const float* __restrict__ cfc_w, const float* __restrict__ cfc_b,
    const float* __restrict__ pfc_w, const float* __restrict__ pfc_b,
    const float* __restrict__ fc1_w, const float* __restrict__ fc1_b,
    const float* __restrict__ out_w, const float* __restrict__ out_b,
    float* __restrict__ out)
{
    __shared__ float cp[512], pp[512], cf[128], pf[128], h[256], red[256];
    int g = blockIdx.x, t = threadIdx.x;
    for (int i = t; i < 512; i += 256) {
        cp[i] = cpool[g * 512 + i];
        pp[i] = ppool[g * 512 + i];
    }
    __syncthreads();
    if (t < 128) {
        float a = cfc_b[t];
        for (int k = 0; k < 512; k++) a += cp[k] * cfc_w[k * 128 + t];
        cf[t] = lrelu(a);
    } else {
        int o = t - 128;
        float a = pfc_b[o];
        for (int k = 0; k < 512; k++) a += pp[k] * pfc_w[k * 128 + o];
        pf[o] = lrelu(a);
    }
    __syncthreads();
    {
        float a = fc1_b[t];
        for (int k = 0; k < 128; k++) a += cf[k] * fc1_w[k * 256 + t];
        for (int k = 0; k < 128; k++) a += pf[k] * fc1_w[(128 + k) * 256 + t];
        h[t] = lrelu(a);
    }
    __syncthreads();
    red[t] = h[t] * out_w[t];
    __syncthreads();
    for (int s = 128; s > 0; s >>= 1) {
        if (t < s) red[t] += red[t + s];
        __syncthreads();
    }
    if (t == 0) out[g] = red[0] + out_b[0];
}

// ---------------------------------------------------------------------------
// launch
// ---------------------------------------------------------------------------
extern "C" void kernel_launch(void* const* d_in, const int* in_sizes, int n_in,
                              void* d_out, int out_size, void* d_ws, size_t ws_size,
                              hipStream_t stream) {
    const float* seq_x      = (const float*)d_in[0];
    const float* compound_x = (const float*)d_in[1];
    const float* conv_w     = (const float*)d_in[2];
    const float* conv_b     = (const float*)d_in[3];
    const float* c1_wl = (const float*)d_in[4];
    const float* c1_bl = (const float*)d_in[5];
    const float* c1_wr = (const float*)d_in[6];
    const float* c2_wl = (const float*)d_in[7];
    const float* c2_bl = (const float*)d_in[8];
    const float* c2_wr = (const float*)d_in[9];
    const float* c3_wl = (const float*)d_in[10];
    const float* c3_bl = (const float*)d_in[11];
    const float* c3_wr = (const float*)d_in[12];
    const float* cfc_w = (const float*)d_in[13];
    const float* cfc_b = (const float*)d_in[14];
    const float* p1_wl = (const float*)d_in[15];
    const float* p1_bl = (const float*)d_in[16];
    const float* p1_wr = (const float*)d_in[17];
    const float* p2_wl = (const float*)d_in[18];
    const float* p2_bl = (const float*)d_in[19];
    const float* p2_wr = (const float*)d_in[20];
    const float* p3_wl = (const float*)d_in[21];
    const float* p3_bl = (const float*)d_in[22];
    const float* p3_wr = (const float*)d_in[23];
    const float* pfc_w = (const float*)d_in[24];
    const float* pfc_b = (const float*)d_in[25];
    const float* fc1_w = (const float*)d_in[26];
    const float* fc1_b = (const float*)d_in[27];
    const float* out_w = (const float*)d_in[28];
    const float* out_b = (const float*)d_in[29];
    const int* prot_gather = (const int*)d_in[30];
    const int* prot_src    = (const int*)d_in[31];
    const int* prot_tgt    = (const int*)d_in[32];
    const int* comp_src    = (const int*)d_in[33];
    const int* comp_tgt    = (const int*)d_in[34];

    float* out = (float*)d_out;

    // workspace layout
    size_t off = 0;
    auto alloc = [&](size_t bytes) -> char* {
        char* p = (char*)d_ws + off;
        off = (off + bytes + 255) & ~(size_t)255;
        return p;
    };
    // fp16 activation buffers
    _Float16* pim   = (_Float16*)alloc((size_t)NP_TOT * 128 * 2);   // im2col
    _Float16* pconv = (_Float16*)alloc((size_t)NP_TOT * 128 * 2);
    _Float16* pagg  = (_Float16*)alloc((size_t)NP_TOT * 256 * 2);
    _Float16* pl1   = (_Float16*)alloc((size_t)NP_TOT * 128 * 2);
    _Float16* pl2   = (_Float16*)alloc((size_t)NP_TOT * 256 * 2);
    _Float16* pl3   = (_Float16*)alloc((size_t)NP_TOT * 512 * 2);
    _Float16* cxp   = (_Float16*)alloc((size_t)NC_TOT * 128 * 2);   // padded to 128
    _Float16* cagg  = (_Float16*)alloc((size_t)NC_TOT * 256 * 2);
    _Float16* cl1   = (_Float16*)alloc((size_t)NC_TOT * 128 * 2);
    _Float16* cl2   = (_Float16*)alloc((size_t)NC_TOT * 256 * 2);
    _Float16* cl3   = (_Float16*)alloc((size_t)NC_TOT * 512 * 2);
    // fp16 transposed weights [D][Kp]
    _Float16* wt_p1l = (_Float16*)alloc(128 * 128 * 2);
    _Float16* wt_p1r = (_Float16*)alloc(128 * 128 * 2);
    _Float16* wt_p2l = (_Float16*)alloc(256 * 128 * 2);
    _Float16* wt_p2r = (_Float16*)alloc(256 * 128 * 2);
    _Float16* wt_p3l = (_Float16*)alloc(512 * 256 * 2);
    _Float16* wt_p3r = (_Float16*)alloc(512 * 256 * 2);
    _Float16* wt_c1l = (_Float16*)alloc(128 * 128 * 2);             // Kp=128
    _Float16* wt_c1r = (_Float16*)alloc(128 * 128 * 2);
    _Float16* wt_c2l = (_Float16*)alloc(256 * 128 * 2);
    _Float16* wt_c2r = (_Float16*)alloc(256 * 128 * 2);
    _Float16* wt_c3l = (_Float16*)alloc(512 * 256 * 2);
    _Float16* wt_c3r = (_Float16*)alloc(512 * 256 * 2);
    _Float16* wt_cv  = (_Float16*)alloc(128 * 128 * 2);
    // pools (f32)
    float* cpool = (float*)alloc(B_GRAPHS * 512 * 4);
    float* ppool = (float*)alloc(B_GRAPHS * 512 * 4);
    float* ppart = (float*)alloc((size_t)B_GRAPHS * PPART * 512 * 4);
    // CSR (cursors contiguous so one zero pass covers both)
    int* cursors  = (int*)alloc((NP_TOT + NC_TOT) * 4);
    int* p_cursor = cursors;
    int* c_cursor = cursors + NP_TOT;
    int* p_rowptr = (int*)alloc((NP_TOT + 1) * 4);
    int* p_csr    = (int*)alloc(EP_TOT * 4);
    int* c_rowptr = (int*)alloc((NC_TOT + 1) * 4);
    int* c_csr    = (int*)alloc(EC_TOT * 4);
    int* bsums    = (int*)alloc(SCAN_NB * 4);
    (void)ws_size; (void)n_in; (void)in_sizes; (void)out_size;

    // ---- weight prep (one launch) + compound input conversion ----
    WJobs jobs;
    jobs.j[0]  = { p1_wl, wt_p1l, 128, 128, 128, 0 };
    jobs.j[1]  = { p1_wr, wt_p1r, 128, 128, 128, 0 };
    jobs.j[2]  = { p2_wl, wt_p2l, 128, 256, 128, 0 };
    jobs.j[3]  = { p2_wr, wt_p2r, 128, 256, 128, 0 };
    jobs.j[4]  = { p3_wl, wt_p3l, 256, 512, 256, 0 };
    jobs.j[5]  = { p3_wr, wt_p3r, 256, 512, 256, 0 };
    jobs.j[6]  = { c1_wl, wt_c1l,  78, 128, 128, 0 };
    jobs.j[7]  = { c1_wr, wt_c1r,  78, 128, 128, 0 };
    jobs.j[8]  = { c2_wl, wt_c2l, 128, 256, 128, 0 };
    jobs.j[9]  = { c2_wr, wt_c2r, 128, 256, 128, 0 };
    jobs.j[10] = { c3_wl, wt_c3l, 256, 512, 256, 0 };
    jobs.j[11] = { c3_wr, wt_c3r, 256, 512, 256, 0 };
    jobs.j[12] = { conv_w, wt_cv, 105, 128, 128, 1 };
    wprep_all_kernel<<<dim3(512, 1, 13), 256, 0, stream>>>(jobs);
    cx_conv_kernel<<<(NC_TOT * 128 + 255) / 256, 256, 0, stream>>>(compound_x, cxp);

    // ---- CSR build (both graphs, fused; parallel scan) ----
    zero_int_kernel<<<(SCAN_N + 255) / 256, 256, 0, stream>>>(cursors, SCAN_N);
    hist2_kernel<<<(EP_TOT + EC_TOT + 255) / 256, 256, 0, stream>>>(prot_tgt, p_cursor, comp_tgt, c_cursor);
    scan_bsum_kernel<<<SCAN_NB, 256, 0, stream>>>(cursors, bsums);
    scan_sums_kernel<<<1, 128, 0, stream>>>(bsums);
    scan_final_kernel<<<SCAN_NB, 256, 0, stream>>>(cursors, bsums, p_rowptr, c_rowptr);
    zero_int_kernel<<<(SCAN_N + 255) / 256, 256, 0, stream>>>(cursors, SCAN_N);
    scatter2_kernel<<<(EP_TOT + EC_TOT + 255) / 256, 256, 0, stream>>>(
        prot_src, prot_tgt, p_rowptr, p_cursor, p_csr,
        comp_src, comp_tgt, c_rowptr, c_cursor, c_csr);

    // ---- conv as im2col + MFMA GEMM -> pconv [NP,128] f16 (no activation) ----
    im2col_kernel<<<(NP_TOT * 32 + 255) / 256, 256, 0, stream>>>(seq_x, prot_gather, pim);
    {
        GemmJob jp = { pim, wt_cv, pim, wt_cv, conv_b, pconv, NP_TOT, 128, 128, 1, 0, NP_TOT / 128 };
        GemmJob jc = jp; jc.nwg = 0;
        gemm_f16_kernel<<<jp.nwg, 256, 0, stream>>>(jp, jc);
    }

    // ---- layer 1 (prot + comp merged) ----
    {
        AggJob ap = { pconv, p_rowptr, p_csr, pagg, NP_TOT, (NP_TOT * 16 + 255) / 256 };
        AggJob ac = { cxp,   c_rowptr, c_csr, cagg, NC_TOT, (NC_TOT * 16 + 255) / 256 };
        agg_f16x8_kernel<128><<<ap.nwg + ac.nwg, 256, 0, stream>>>(ap, ac);
        GemmJob jp = { pagg, wt_p1l, pconv, wt_p1r, p1_bl, pl1, NP_TOT, 128, 128, 2, 1, NP_TOT / 128 };
        GemmJob jc = { cagg, wt_c1l, cxp,   wt_c1r, c1_bl, cl1, NC_TOT, 128, 128, 2, 1, NC_TOT / 128 };
        gemm_f16_kernel<<<jp.nwg + jc.nwg, 256, 0, stream>>>(jp, jc);
    }
    // ---- layer 2 ----
    {
        AggJob ap = { pl1, p_rowptr, p_csr, pagg, NP_TOT, (NP_TOT * 16 + 255) / 256 };
        AggJob ac = { cl1, c_rowptr, c_csr, cagg, NC_TOT, (NC_TOT * 16 + 255) / 256 };
        agg_f16x8_kernel<128><<<ap.nwg + ac.nwg, 256, 0, stream>>>(ap, ac);
        GemmJob jp = { pagg, wt_p2l, pl1, wt_p2r, p2_bl, pl2, NP_TOT, 128, 256, 2, 1, (NP_TOT / 128) * 2 };
        GemmJob jc = { cagg, wt_c2l, cl1, wt_c2r, c2_bl, cl2, NC_TOT, 128, 256, 2, 1, (NC_TOT / 128) * 2 };
        gemm_f16_kernel<<<jp.nwg + jc.nwg, 256, 0, stream>>>(jp, jc);
    }
    // ---- layer 3 ----
    {
        AggJob ap = { pl2, p_rowptr, p_csr, pagg, NP_TOT, (NP_TOT * 32 + 255) / 256 };
        AggJob ac = { cl2, c_rowptr, c_csr, cagg, NC_TOT, (NC_TOT * 32 + 255) / 256 };
        agg_f16x8_kernel<256><<<ap.nwg + ac.nwg, 256, 0, stream>>>(ap, ac);
        GemmJob jp = { pagg, wt_p3l, pl2, wt_p3r, p3_bl, pl3, NP_TOT, 256, 512, 2, 1, (NP_TOT / 128) * 4 };
        GemmJob jc = { cagg, wt_c3l, cl2, wt_c3r, c3_bl, cl3, NC_TOT, 256, 512, 2, 1, (NC_TOT / 128) * 4 };
        gemm_f16_kernel<<<jp.nwg + jc.nwg, 256, 0, stream>>>(jp, jc);
    }

    // ---- pooling ----
    pool_comp_kernel<<<B_GRAPHS, 256, 0, stream>>>(cl3, cpool);
    pool_prot_partial_kernel<<<dim3(B_GRAPHS, PSPLIT), 256, 0, stream>>>(pl3, ppart);
    pool_prot_final_kernel<<<dim3(B_GRAPHS, 2), 256, 0, stream>>>(ppart, ppool);

    // ---- head ----
    head_kernel<<<B_GRAPHS, 256, 0, stream>>>(cpool, ppool, cfc_w, cfc_b, pfc_w, pfc_b,
                                              fc1_w, fc1_b, out_w, out_b, out);
}